// Round 1
// 267.304 us; speedup vs baseline: 1.0017x; 1.0017x over previous
//
#include <hip/hip_runtime.h>
#include <math.h>

// Time2Vec: out[b,l,d,e] = (e==0) ? x[b,l,d]*W[d,0]+b[d,0]
//                                 : sin(x[b,l,d]*W[d,e]+b[d,e])
// B=32 L=4096 D=8 E=64. Output 256 MiB fp32 -> write-BW-bound.
// Floor: 268 MB / 6.4 TB/s (measured fill rate) ~= 42 us kernel-side.
// NOTE: harness-timed region includes a 1 GiB poison fill (~170 us) --
// rocprof top-5 shows only fills at 166-175 us, so the kernel itself is
// <166 us and dur_us floor is ~212 us, not 42.
//
// R1 experiment: plain stores instead of nontemporal. The 6.4 TB/s rocclr
// fill uses plain dwordx4 stores; 'nt' (no-allocate) is the only structural
// difference between our store path and theirs. VALU/occupancy arithmetic
// rules out everything else (VALU-limited BW ~46 TB/s >> HBM).

#define T2V_E   64
#define T2V_DE  512   // D*E

typedef float fx4 __attribute__((ext_vector_type(4)));

__global__ __launch_bounds__(256) void t2v_kernel(
    const float* __restrict__ x,    // B*L*D
    const float* __restrict__ W,    // 512
    const float* __restrict__ bias, // 512
    fx4* __restrict__ out)          // B*L*D*E / 4 float4s
{
    __shared__ float4 sW[T2V_DE / 4];
    __shared__ float4 sB[T2V_DE / 4];
    const int t = threadIdx.x;
    if (t < T2V_DE / 4) {
        sW[t] = ((const float4*)W)[t];
        sB[t] = ((const float4*)bias)[t];
    }
    __syncthreads();

    // Each block covers 1024 consecutive float4s (4 per thread, stride 256).
    const int base = blockIdx.x * 1024 + t;   // float4 index of k=0

    // wi = i & 127 is identical for all 4 k (256 % 128 == 0): load W/b once.
    const int wi = (base & 127);
    const float4 w = sW[wi];
    const float4 c = sB[wi];

    // Hoist the 4 x loads: (base + k*256)>>4 == (base>>4) + k*16 exactly
    // (k*256 has low 8 bits clear, no carry into the shifted-out bits).
    const int xb = base >> 4;
    float xv[4];
#pragma unroll
    for (int k = 0; k < 4; ++k) xv[k] = x[xb + k * 16];

#pragma unroll
    for (int k = 0; k < 4; ++k) {
        const int i = base + k * 256;         // float4 index
        float ax = fmaf(xv[k], w.x, c.x);
        float ay = fmaf(xv[k], w.y, c.y);
        float az = fmaf(xv[k], w.z, c.z);
        float aw = fmaf(xv[k], w.w, c.w);
        fx4 o;
        o.x = ((i & 15) == 0) ? ax : __sinf(ax);  // e==0 only at i%16==0, lane .x
        o.y = __sinf(ay);
        o.z = __sinf(az);
        o.w = __sinf(aw);
        out[i] = o;                           // plain store: through L2 writeback
    }
}

extern "C" void kernel_launch(void* const* d_in, const int* in_sizes, int n_in,
                              void* d_out, int out_size, void* d_ws, size_t ws_size,
                              hipStream_t stream) {
    const float* x    = (const float*)d_in[0];
    const float* W    = (const float*)d_in[1];
    const float* bias = (const float*)d_in[2];
    fx4* out = (fx4*)d_out;

    // out_size = 67108864 floats = 16777216 float4 = 16384 blocks * 1024
    const int blocks = (out_size >> 2) / 1024;
    t2v_kernel<<<blocks, 256, 0, stream>>>(x, W, bias, out);
}

// Round 2
// 264.990 us; speedup vs baseline: 1.0104x; 1.0087x over previous
//
#include <hip/hip_runtime.h>
#include <math.h>

// Time2Vec: out[b,l,d,e] = (e==0) ? x[b,l,d]*W[d,0]+b[d,0]
//                                 : sin(x[b,l,d]*W[d,e]+b[d,e])
// B=32 L=4096 D=8 E=64. Output 256 MiB fp32 -> write-BW-bound.
// Kernel-side floor: 272 MB / 6.4 TB/s (measured fill rate) ~= 42 us.
// Timed region also contains a ~166 us 1 GiB poison fill (rocprof top-5 is
// all fills; our kernel never appears, so it is < 165 us).
//
// R2: persistent-grid restructure. Old shape: 16384 tiny blocks x 16 KiB,
// each paying LDS staging (4 KiB W/b, half the threads idle) + __syncthreads
// + prologue, 8 occupancy rounds with drain tail. New shape mirrors the
// 6.4 TB/s fill kernel: 2048 blocks (exactly 8/CU), no LDS, no sync,
// W/b in 8 registers (wi = t&127 is loop-invariant per thread),
// x8-unrolled loop with x-loads hoisted ahead of the sin chains.

#define NTHR   256
#define NBLK   2048
#define UNROLL 8

typedef float fx4 __attribute__((ext_vector_type(4)));

__global__ __launch_bounds__(256) void t2v_kernel(
    const float* __restrict__ x,    // B*L*D floats
    const float* __restrict__ W,    // 512 floats
    const float* __restrict__ bias, // 512 floats
    fx4* __restrict__ out,          // B*L*D*E/4 float4s
    int total_f4)                   // 16777216
{
    const int t  = threadIdx.x;
    const int wi = t & 127;               // float4 position within 512-float (d,e) row
    // Per-thread affine params: one float4 of W and bias, loop-invariant.
    // Loaded once from global (L2-broadcast across all blocks). No LDS, no sync.
    const float4 w = ((const float4*)W)[wi];
    const float4 c = ((const float4*)bias)[wi];
    const bool  e0 = (wi & 15) == 0;      // this thread's .x lane is e==0

    const int per_block = total_f4 / NBLK;        // 8192 float4 = 128 KiB contiguous
    const int iters     = per_block / NTHR;       // 32
    const int base      = blockIdx.x * per_block + t;
    const int xbase     = (blockIdx.x * per_block) >> 4;
    const int xt        = t >> 4;                 // 16 float4s per x element

    for (int it0 = 0; it0 < iters; it0 += UNROLL) {
        // Hoist UNROLL x-loads (independent, all in flight together).
        float xv[UNROLL];
#pragma unroll
        for (int u = 0; u < UNROLL; ++u)
            xv[u] = x[xbase + (it0 + u) * 16 + xt];

#pragma unroll
        for (int u = 0; u < UNROLL; ++u) {
            const int i = base + (it0 + u) * 256;  // float4 index; i&15 == t&15
            float ax = fmaf(xv[u], w.x, c.x);
            float ay = fmaf(xv[u], w.y, c.y);
            float az = fmaf(xv[u], w.z, c.z);
            float aw = fmaf(xv[u], w.w, c.w);
            fx4 o;
            o.x = e0 ? ax : __sinf(ax);   // e==0 passes through un-sined
            o.y = __sinf(ay);
            o.z = __sinf(az);
            o.w = __sinf(aw);
            out[i] = o;                   // wave-contiguous 1 KiB store
        }
    }
}

extern "C" void kernel_launch(void* const* d_in, const int* in_sizes, int n_in,
                              void* d_out, int out_size, void* d_ws, size_t ws_size,
                              hipStream_t stream) {
    const float* x    = (const float*)d_in[0];
    const float* W    = (const float*)d_in[1];
    const float* bias = (const float*)d_in[2];
    fx4* out = (fx4*)d_out;

    const int total_f4 = out_size >> 2;   // 16777216 for B32 L4096 D8 E64
    t2v_kernel<<<NBLK, NTHR, 0, stream>>>(x, W, bias, out, total_f4);
}